// Round 1
// baseline (237.674 us; speedup 1.0000x reference)
//
#include <hip/hip_runtime.h>
#include <math.h>

#define BB 128
#define SS 1024
#define DD 256
#define NP (BB * SS)      // 131072 points
#define CH 8              // S-chunks per b in K1
#define ROWS (SS / CH)    // 128 rows per chunk
#define NB3 1024          // blocks for the two big sweep kernels

// ---- wave (64-lane) sum via xor shuffle ----
__device__ __forceinline__ float wave_sum(float v) {
#pragma unroll
    for (int m = 32; m >= 1; m >>= 1) v += __shfl_xor(v, m, 64);
    return v;
}

// ---- block (256-thread) tree sum; result broadcast to all threads ----
__device__ __forceinline__ float block_sum(float v, float* red) {
    const int t = threadIdx.x;
    red[t] = v;
    __syncthreads();
#pragma unroll
    for (int off = 128; off >= 1; off >>= 1) {
        if (t < off) red[t] += red[t + off];
        __syncthreads();
    }
    float r = red[0];
    __syncthreads();
    return r;
}

// K1: partial sums over S-chunks: part[b][ch][d] = sum_{s in chunk} x[b,s,d]
__global__ __launch_bounds__(256) void k1_partial(const float* __restrict__ x,
                                                  float* __restrict__ part) {
    const int ch = blockIdx.x, b = blockIdx.y;
    const int w = threadIdx.x >> 6, l = threadIdx.x & 63;
    const float4* x4 = (const float4*)x;
    // wave w handles rows [w*32, w*32+32) of this chunk; lane l owns features 4l..4l+3
    size_t base = ((size_t)b * SS + (size_t)ch * ROWS + (size_t)w * (ROWS / 4)) * (DD / 4);
    float4 s = make_float4(0.f, 0.f, 0.f, 0.f);
    for (int r = 0; r < ROWS / 4; ++r) {
        float4 v = x4[base + (size_t)r * (DD / 4) + l];
        s.x += v.x; s.y += v.y; s.z += v.z; s.w += v.w;
    }
    __shared__ float lds[4][DD];
    lds[w][4 * l + 0] = s.x; lds[w][4 * l + 1] = s.y;
    lds[w][4 * l + 2] = s.z; lds[w][4 * l + 3] = s.w;
    __syncthreads();
    const int t = threadIdx.x;
    part[((size_t)b * CH + ch) * DD + t] = lds[0][t] + lds[1][t] + lds[2][t] + lds[3][t];
}

// K2a: per-b Lorentz centroid over S: c1[b][d]
__global__ __launch_bounds__(256) void k2a_c1(const float* __restrict__ part,
                                              float* __restrict__ c1) {
    const int b = blockIdx.x;
    const int t = threadIdx.x;
    __shared__ float red[DD];
    float sx = 0.f;
#pragma unroll
    for (int ch = 0; ch < CH; ++ch) sx += part[((size_t)b * CH + ch) * DD + t];
    float avg = sx * (1.0f / SS);
    // -linner(avg,avg) = avg0^2 - sum_{i>=1} avg_i^2
    float contrib = (t == 0) ? avg * avg : -avg * avg;
    float r = block_sum(contrib, red);
    float denom = sqrtf(fmaxf(fabsf(r), 1e-8f));
    c1[(size_t)b * DD + t] = avg / denom;
}

// K2b: Lorentz centroid over B of c1 -> mean[d] (to d_ws)
__global__ __launch_bounds__(256) void k2b_mean(const float* __restrict__ c1,
                                                float* __restrict__ wsmean) {
    const int t = threadIdx.x;
    __shared__ float red[DD];
    float acc = 0.f;
#pragma unroll 8
    for (int b = 0; b < BB; ++b) acc += c1[(size_t)b * DD + t];
    float avg = acc * (1.0f / BB);
    float contrib = (t == 0) ? avg * avg : -avg * avg;
    float r = block_sum(contrib, red);
    float denom = sqrtf(fmaxf(fabsf(r), 1e-8f));
    wsmean[t] = avg / denom;
}

// x_t' = transp0back(mean, logmap(mean, y)) for one point (wave-per-point; lane l owns feats 4l..4l+3)
__device__ __forceinline__ float4 compute_xt(const float4* __restrict__ row, int l,
                                             float4 m4, float m0, float inv1pm0) {
    float4 v = row[l];
    float dp = v.x * m4.x + v.y * m4.y + v.z * m4.z + v.w * m4.w;
    float dot = wave_sum(dp);                 // sum_all mean_i * y_i
    float y0 = __shfl(v.x, 0, 64);            // feature 0
    // alpha = -linner(mean,y) = 2*m0*y0 - dot, clipped at 1+1e-7
    float alpha = fmaxf(2.0f * m0 * y0 - dot, 1.0f + 1e-7f);
    float f = acoshf(alpha) / sqrtf(fmaf(alpha, alpha, -1.0f));
    float xt0 = f * (y0 - alpha * m0);
    float coef = xt0 * inv1pm0;               // xt0 / (1 + mean0)
    float4 r;
    r.x = f * (v.x - alpha * m4.x) - coef * ((l == 0) ? (m0 + 1.0f) : m4.x);
    r.y = f * (v.y - alpha * m4.y) - coef * m4.y;
    r.z = f * (v.z - alpha * m4.z) - coef * m4.z;
    r.w = f * (v.w - alpha * m4.w) - coef * m4.w;
    return r;
}

// K3: per-feature partial sum and sumsq of x_t' over points
__global__ __launch_bounds__(256) void k3_stats(const float* __restrict__ x,
                                                const float* __restrict__ wsmean,
                                                float* __restrict__ part3) {
    const int w = threadIdx.x >> 6, l = threadIdx.x & 63;
    float4 m4 = ((const float4*)wsmean)[l];
    float m0 = wsmean[0];
    float inv1pm0 = 1.0f / (1.0f + m0);
    float4 s = make_float4(0, 0, 0, 0), q = make_float4(0, 0, 0, 0);
    const int wid = blockIdx.x * 4 + w;
    for (int p = wid; p < NP; p += NB3 * 4) {
        const float4* row = ((const float4*)x) + (size_t)p * (DD / 4);
        float4 t4 = compute_xt(row, l, m4, m0, inv1pm0);
        s.x += t4.x; s.y += t4.y; s.z += t4.z; s.w += t4.w;
        q.x += t4.x * t4.x; q.y += t4.y * t4.y; q.z += t4.z * t4.z; q.w += t4.w * t4.w;
    }
    __shared__ float lds[4][2 * DD];
    lds[w][4 * l + 0] = s.x; lds[w][4 * l + 1] = s.y;
    lds[w][4 * l + 2] = s.z; lds[w][4 * l + 3] = s.w;
    lds[w][DD + 4 * l + 0] = q.x; lds[w][DD + 4 * l + 1] = q.y;
    lds[w][DD + 4 * l + 2] = q.z; lds[w][DD + 4 * l + 3] = q.w;
    __syncthreads();
    const int t = threadIdx.x;
    part3[(size_t)blockIdx.x * (2 * DD) + t]      = lds[0][t] + lds[1][t] + lds[2][t] + lds[3][t];
    part3[(size_t)blockIdx.x * (2 * DD) + DD + t] = lds[0][DD + t] + lds[1][DD + t] + lds[2][DD + t] + lds[3][DD + t];
}

// K4: reduce partials -> scale[d] = gamma / sqrt(var + 1e-5) (to d_ws)
__global__ __launch_bounds__(256) void k4_scale(const float* __restrict__ part3,
                                                const float* __restrict__ gamma,
                                                float* __restrict__ wsscale) {
    const int t = threadIdx.x;
    double s1 = 0.0, s2 = 0.0;
    for (int i = 0; i < NB3; ++i) {
        s1 += (double)part3[(size_t)i * (2 * DD) + t];
        s2 += (double)part3[(size_t)i * (2 * DD) + DD + t];
    }
    const double N = (double)NP;
    double mv = s1 / N;
    double var = s2 / N - mv * mv;
    float stdv = sqrtf((float)var + 1e-5f);
    wsscale[t] = gamma[0] / stdv;
}

// K5: recompute x_t', scale, transp0(beta), expmap(beta), store
__global__ __launch_bounds__(256) void k5_out(const float* __restrict__ x,
                                              const float* __restrict__ wsmean,
                                              const float* __restrict__ wsscale,
                                              const float* __restrict__ beta,
                                              float4* __restrict__ out4) {
    const int w = threadIdx.x >> 6, l = threadIdx.x & 63;
    float4 m4 = ((const float4*)wsmean)[l];
    float m0 = wsmean[0];
    float inv1pm0 = 1.0f / (1.0f + m0);
    float4 sc = ((const float4*)wsscale)[l];
    float4 b4 = ((const float4*)beta)[l];
    float b0 = beta[0];
    float inv1pb0 = 1.0f / (1.0f + b0);
    const int wid = blockIdx.x * 4 + w;
    for (int p = wid; p < NP; p += NB3 * 4) {
        const float4* row = ((const float4*)x) + (size_t)p * (DD / 4);
        float4 t4 = compute_xt(row, l, m4, m0, inv1pm0);
        float4 v = make_float4(t4.x * sc.x, t4.y * sc.y, t4.z * sc.z, t4.w * sc.w);
        // transp0(beta, v): coef = linner(beta,v)/(1+b0); w = v + coef*add_origin(beta)
        float dpb = v.x * b4.x + v.y * b4.y + v.z * b4.z + v.w * b4.w;
        float dotb = wave_sum(dpb);
        float v0 = __shfl(v.x, 0, 64);
        float lin = dotb - 2.0f * b0 * v0;
        float coef = lin * inv1pb0;
        float4 wv;
        wv.x = v.x + coef * ((l == 0) ? (b0 + 1.0f) : b4.x);
        wv.y = v.y + coef * b4.y;
        wv.z = v.z + coef * b4.z;
        wv.w = v.w + coef * b4.w;
        // expmap(beta, wv): n = sqrt(clip(linner(wv,wv),1e-7)); out = cosh(n)*beta + sinh(n)*wv/n
        float dq = wv.x * wv.x + wv.y * wv.y + wv.z * wv.z + wv.w * wv.w;
        float dotw = wave_sum(dq);
        float w0 = v0 + coef * (b0 + 1.0f);   // wv at feature 0 (uniform across lanes)
        float nn = dotw - 2.0f * w0 * w0;     // linner(wv,wv)
        float n = sqrtf(fmaxf(nn, 1e-7f));
        float chn = coshf(n);
        float shn = sinhf(n) / n;
        float4 o;
        o.x = chn * ((l == 0) ? b0 : b4.x) + shn * wv.x;
        o.y = chn * b4.y + shn * wv.y;
        o.z = chn * b4.z + shn * wv.z;
        o.w = chn * b4.w + shn * wv.w;
        out4[(size_t)p * (DD / 4) + l] = o;
    }
}

extern "C" void kernel_launch(void* const* d_in, const int* in_sizes, int n_in,
                              void* d_out, int out_size, void* d_ws, size_t ws_size,
                              hipStream_t stream) {
    (void)in_sizes; (void)n_in; (void)out_size; (void)ws_size;
    const float* x     = (const float*)d_in[0];
    const float* beta  = (const float*)d_in[1];
    const float* gamma = (const float*)d_in[2];
    float* out = (float*)d_out;

    // Small persistent values live in d_ws (2 KB): mean[256], scale[256].
    float* wsmean  = (float*)d_ws;
    float* wsscale = wsmean + DD;

    // Large scratch lives in d_out (fully overwritten by K5 last; kernels serialize on stream):
    float* part  = out;                         // [B][CH][D]  = 262144 floats
    float* c1    = out + (size_t)BB * CH * DD;  // [B][D]      =  32768 floats (consumed before K3 overwrites)
    float* part3 = out;                         // [NB3][2*D]  = 524288 floats

    k1_partial<<<dim3(CH, BB), 256, 0, stream>>>(x, part);
    k2a_c1<<<BB, 256, 0, stream>>>(part, c1);
    k2b_mean<<<1, 256, 0, stream>>>(c1, wsmean);
    k3_stats<<<NB3, 256, 0, stream>>>(x, wsmean, part3);
    k4_scale<<<1, 256, 0, stream>>>(part3, gamma, wsscale);
    k5_out<<<NB3, 256, 0, stream>>>(x, wsmean, wsscale, beta, (float4*)out);
}

// Round 2
// 106.106 us; speedup vs baseline: 2.2400x; 2.2400x over previous
//
#include <hip/hip_runtime.h>
#include <math.h>

#define BB 128
#define SS 1024
#define DD 256
#define NP (BB * SS)      // 131072 points
#define CH 16             // S-chunks per b in K1
#define ROWS (SS / CH)    // 64 rows per chunk
#define NB3 2048          // blocks for the two big sweep kernels (8 waves/SIMD)
#define NW3 (NB3 * 4)     // 8192 waves
#define RB4 32            // part3 rows per K4a block
#define NB4A (NB3 / RB4)  // 64 blocks in K4a

// ---- fast HW transcendentals (v_exp_f32 is exp2, v_log_f32 is log2) ----
#define LN2F 0.69314718056f
#define L2EF 1.44269504089f
__device__ __forceinline__ float fsqrt(float x) { return __builtin_amdgcn_sqrtf(x); }
__device__ __forceinline__ float frcp(float x)  { return __builtin_amdgcn_rcpf(x); }
__device__ __forceinline__ float frsq(float x)  { return __builtin_amdgcn_rsqf(x); }
__device__ __forceinline__ float flog2(float x) { return __builtin_amdgcn_logf(x); }
__device__ __forceinline__ float fexp2(float x) { return __builtin_amdgcn_exp2f(x); }

// ---- wave (64-lane) sum via xor shuffle ----
__device__ __forceinline__ float wave_sum(float v) {
#pragma unroll
    for (int m = 32; m >= 1; m >>= 1) v += __shfl_xor(v, m, 64);
    return v;
}

// ---- block (256-thread) tree sum; result broadcast to all threads ----
__device__ __forceinline__ float block_sum(float v, float* red) {
    const int t = threadIdx.x;
    red[t] = v;
    __syncthreads();
#pragma unroll
    for (int off = 128; off >= 1; off >>= 1) {
        if (t < off) red[t] += red[t + off];
        __syncthreads();
    }
    float r = red[0];
    __syncthreads();
    return r;
}

// K1: partial sums over S-chunks: part[b][ch][d] = sum_{s in chunk} x[b,s,d]
__global__ __launch_bounds__(256) void k1_partial(const float* __restrict__ x,
                                                  float* __restrict__ part) {
    const int ch = blockIdx.x, b = blockIdx.y;
    const int w = threadIdx.x >> 6, l = threadIdx.x & 63;
    const float4* x4 = (const float4*)x;
    size_t base = ((size_t)b * SS + (size_t)ch * ROWS + (size_t)w * (ROWS / 4)) * (DD / 4);
    float4 s = make_float4(0.f, 0.f, 0.f, 0.f);
#pragma unroll 4
    for (int r = 0; r < ROWS / 4; ++r) {
        float4 v = x4[base + (size_t)r * (DD / 4) + l];
        s.x += v.x; s.y += v.y; s.z += v.z; s.w += v.w;
    }
    __shared__ float lds[4][DD];
    lds[w][4 * l + 0] = s.x; lds[w][4 * l + 1] = s.y;
    lds[w][4 * l + 2] = s.z; lds[w][4 * l + 3] = s.w;
    __syncthreads();
    const int t = threadIdx.x;
    part[((size_t)b * CH + ch) * DD + t] = lds[0][t] + lds[1][t] + lds[2][t] + lds[3][t];
}

// K2a: per-b Lorentz centroid over S: c1[b][d]
__global__ __launch_bounds__(256) void k2a_c1(const float* __restrict__ part,
                                              float* __restrict__ c1) {
    const int b = blockIdx.x;
    const int t = threadIdx.x;
    __shared__ float red[DD];
    float sx = 0.f;
#pragma unroll
    for (int ch = 0; ch < CH; ++ch) sx += part[((size_t)b * CH + ch) * DD + t];
    float avg = sx * (1.0f / SS);
    float contrib = (t == 0) ? avg * avg : -avg * avg;
    float r = block_sum(contrib, red);
    c1[(size_t)b * DD + t] = avg * frsq(fmaxf(fabsf(r), 1e-8f));
}

// K2b: Lorentz centroid over B of c1 -> mean[d] (to d_ws)
__global__ __launch_bounds__(256) void k2b_mean(const float* __restrict__ c1,
                                                float* __restrict__ wsmean) {
    const int t = threadIdx.x;
    __shared__ float red[DD];
    float acc = 0.f;
#pragma unroll 8
    for (int b = 0; b < BB; ++b) acc += c1[(size_t)b * DD + t];
    float avg = acc * (1.0f / BB);
    float contrib = (t == 0) ? avg * avg : -avg * avg;
    float r = block_sum(contrib, red);
    wsmean[t] = avg * frsq(fmaxf(fabsf(r), 1e-8f));
}

// x_t' = transp0back(mean, logmap(mean, y)); wave-per-point, lane l owns feats 4l..4l+3
__device__ __forceinline__ float4 compute_xt(const float4* __restrict__ row, int l,
                                             float4 m4, float m0, float inv1pm0) {
    float4 v = row[l];
    float dp = fmaf(v.x, m4.x, fmaf(v.y, m4.y, fmaf(v.z, m4.z, v.w * m4.w)));
    float dot = wave_sum(dp);                 // sum_all mean_i * y_i
    float y0 = __shfl(v.x, 0, 64);            // feature 0
    float alpha = fmaxf(fmaf(2.0f * m0, y0, -dot), 1.0f + 1e-7f);
    float t = fmaf(alpha, alpha, -1.0f);
    // f = acosh(alpha)/sqrt(alpha^2-1) = ln2*log2(alpha+sqrt(t)) * rsqrt(t)
    float f = (LN2F * flog2(alpha + fsqrt(t))) * frsq(t);
    float xt0 = f * (y0 - alpha * m0);
    float coef = xt0 * inv1pm0;               // xt0 / (1 + mean0)
    float4 r;
    r.x = f * (v.x - alpha * m4.x) - coef * ((l == 0) ? (m0 + 1.0f) : m4.x);
    r.y = f * (v.y - alpha * m4.y) - coef * m4.y;
    r.z = f * (v.z - alpha * m4.z) - coef * m4.z;
    r.w = f * (v.w - alpha * m4.w) - coef * m4.w;
    return r;
}

// K3: per-feature partial sum and sumsq of x_t' over points
__global__ __launch_bounds__(256) void k3_stats(const float* __restrict__ x,
                                                const float* __restrict__ wsmean,
                                                float* __restrict__ part3) {
    const int w = threadIdx.x >> 6, l = threadIdx.x & 63;
    float4 m4 = ((const float4*)wsmean)[l];
    float m0 = wsmean[0];
    float inv1pm0 = frcp(1.0f + m0);
    float4 s = make_float4(0, 0, 0, 0), q = make_float4(0, 0, 0, 0);
    const int wid = blockIdx.x * 4 + w;
#pragma unroll 2
    for (int p = wid; p < NP; p += NW3) {
        const float4* row = ((const float4*)x) + (size_t)p * (DD / 4);
        float4 t4 = compute_xt(row, l, m4, m0, inv1pm0);
        s.x += t4.x; s.y += t4.y; s.z += t4.z; s.w += t4.w;
        q.x += t4.x * t4.x; q.y += t4.y * t4.y; q.z += t4.z * t4.z; q.w += t4.w * t4.w;
    }
    __shared__ float lds[4][2 * DD];
    lds[w][4 * l + 0] = s.x; lds[w][4 * l + 1] = s.y;
    lds[w][4 * l + 2] = s.z; lds[w][4 * l + 3] = s.w;
    lds[w][DD + 4 * l + 0] = q.x; lds[w][DD + 4 * l + 1] = q.y;
    lds[w][DD + 4 * l + 2] = q.z; lds[w][DD + 4 * l + 3] = q.w;
    __syncthreads();
    const int t = threadIdx.x;
    part3[(size_t)blockIdx.x * (2 * DD) + t]      = lds[0][t] + lds[1][t] + lds[2][t] + lds[3][t];
    part3[(size_t)blockIdx.x * (2 * DD) + DD + t] = lds[0][DD + t] + lds[1][DD + t] + lds[2][DD + t] + lds[3][DD + t];
}

// K4a: reduce part3 rows 32-at-a-time: stage2[blk][c] = sum over 32 rows
__global__ __launch_bounds__(512) void k4a_reduce(const float* __restrict__ part3,
                                                  float* __restrict__ stage2) {
    const int t = threadIdx.x;            // column 0..511
    const int r0 = blockIdx.x * RB4;
    float s = 0.f;
#pragma unroll 8
    for (int r = 0; r < RB4; ++r) s += part3[(size_t)(r0 + r) * (2 * DD) + t];
    stage2[(size_t)blockIdx.x * (2 * DD) + t] = s;
}

// K4b: final reduce -> scale[d] = gamma * rsqrt(var + 1e-5) (to d_ws)
__global__ __launch_bounds__(256) void k4b_scale(const float* __restrict__ stage2,
                                                 const float* __restrict__ gamma,
                                                 float* __restrict__ wsscale) {
    const int t = threadIdx.x;
    double s1 = 0.0, s2 = 0.0;
    for (int i = 0; i < NB4A; ++i) {
        s1 += (double)stage2[(size_t)i * (2 * DD) + t];
        s2 += (double)stage2[(size_t)i * (2 * DD) + DD + t];
    }
    const double N = (double)NP;
    double mv = s1 / N;
    double var = s2 / N - mv * mv;
    wsscale[t] = gamma[0] * frsq((float)var + 1e-5f);
}

// K5: recompute x_t', scale, transp0(beta), expmap(beta), store
__global__ __launch_bounds__(256) void k5_out(const float* __restrict__ x,
                                              const float* __restrict__ wsmean,
                                              const float* __restrict__ wsscale,
                                              const float* __restrict__ beta,
                                              float4* __restrict__ out4) {
    const int w = threadIdx.x >> 6, l = threadIdx.x & 63;
    float4 m4 = ((const float4*)wsmean)[l];
    float m0 = wsmean[0];
    float inv1pm0 = frcp(1.0f + m0);
    float4 sc = ((const float4*)wsscale)[l];
    float4 b4 = ((const float4*)beta)[l];
    float b0 = beta[0];
    float inv1pb0 = frcp(1.0f + b0);
    const int wid = blockIdx.x * 4 + w;
#pragma unroll 2
    for (int p = wid; p < NP; p += NW3) {
        const float4* row = ((const float4*)x) + (size_t)p * (DD / 4);
        float4 t4 = compute_xt(row, l, m4, m0, inv1pm0);
        float4 v = make_float4(t4.x * sc.x, t4.y * sc.y, t4.z * sc.z, t4.w * sc.w);
        // transp0(beta, v): coef = linner(beta,v)/(1+b0); wv = v + coef*add_origin(beta)
        float dpb = fmaf(v.x, b4.x, fmaf(v.y, b4.y, fmaf(v.z, b4.z, v.w * b4.w)));
        float dotb = wave_sum(dpb);
        float v0 = __shfl(v.x, 0, 64);
        float coef = (dotb - 2.0f * b0 * v0) * inv1pb0;
        float4 wv;
        wv.x = v.x + coef * ((l == 0) ? (b0 + 1.0f) : b4.x);
        wv.y = v.y + coef * b4.y;
        wv.z = v.z + coef * b4.z;
        wv.w = v.w + coef * b4.w;
        // expmap(beta, wv): n = sqrt(clip(linner(wv,wv),1e-7)); out = cosh(n)*beta + sinh(n)*wv/n
        float dq = fmaf(wv.x, wv.x, fmaf(wv.y, wv.y, fmaf(wv.z, wv.z, wv.w * wv.w)));
        float dotw = wave_sum(dq);
        float w0 = v0 + coef * (b0 + 1.0f);   // wv feature 0 (uniform across lanes)
        float nn = fmaxf(dotw - 2.0f * w0 * w0, 1e-7f);
        float n = fsqrt(nn);
        float e = fexp2(n * L2EF);            // e^n
        float ei = frcp(e);                   // e^-n
        float chn = 0.5f * (e + ei);
        float shn = 0.5f * (e - ei) * frsq(nn);  // sinh(n)/n
        float4 o;
        o.x = chn * ((l == 0) ? b0 : b4.x) + shn * wv.x;
        o.y = chn * b4.y + shn * wv.y;
        o.z = chn * b4.z + shn * wv.z;
        o.w = chn * b4.w + shn * wv.w;
        out4[(size_t)p * (DD / 4) + l] = o;
    }
}

extern "C" void kernel_launch(void* const* d_in, const int* in_sizes, int n_in,
                              void* d_out, int out_size, void* d_ws, size_t ws_size,
                              hipStream_t stream) {
    (void)in_sizes; (void)n_in; (void)out_size; (void)ws_size;
    const float* x     = (const float*)d_in[0];
    const float* beta  = (const float*)d_in[1];
    const float* gamma = (const float*)d_in[2];
    float* out = (float*)d_out;

    // Small persistent values live in d_ws (2 KB): mean[256], scale[256].
    float* wsmean  = (float*)d_ws;
    float* wsscale = wsmean + DD;

    // Large scratch lives in d_out (fully overwritten by K5 last; kernels serialize on stream):
    float* part   = out;                          // [B][CH][D]   = 524288 floats
    float* c1     = out + (size_t)BB * CH * DD;   // [B][D]       =  32768 floats (consumed before K3)
    float* part3  = out;                          // [NB3][2*D]   = 1048576 floats
    float* stage2 = out + (size_t)NB3 * 2 * DD;   // [NB4A][2*D]  =  32768 floats

    k1_partial<<<dim3(CH, BB), 256, 0, stream>>>(x, part);
    k2a_c1<<<BB, 256, 0, stream>>>(part, c1);
    k2b_mean<<<1, 256, 0, stream>>>(c1, wsmean);
    k3_stats<<<NB3, 256, 0, stream>>>(x, wsmean, part3);
    k4a_reduce<<<NB4A, 512, 0, stream>>>(part3, stage2);
    k4b_scale<<<1, 256, 0, stream>>>(stage2, gamma, wsscale);
    k5_out<<<NB3, 256, 0, stream>>>(x, wsmean, wsscale, beta, (float4*)out);
}